// Round 2
// 2802.196 us; speedup vs baseline: 1.2150x; 1.2150x over previous
//
// LSTM trajectory autoencoder, MI355X gfx950 — R5: tagged self-validating
// exchange. R4 post-mortem: all pipes idle (Mfma 4.5%, VALU 12.8%, HBM 1.6%),
// ~7.7k cy/step across ~1024 sequential steps -> per-step latency chain:
// publish vmcnt(0) drains at __syncthreads + separate flag RT + serial data RT
// + x-load latency. R5: data word = (bf16 | tag<<16), per-dword atomic ->
// data IS the flag (one RT, fire-and-forget publish, no flags, no fences);
// all loop barriers are raw lgkm-only s_barrier (no vmcnt drain); x prefetched
// one step ahead in regs.
#include <hip/hip_runtime.h>

typedef unsigned short u16;
typedef unsigned u32;
typedef unsigned long long u64;
typedef float f32x4 __attribute__((ext_vector_type(4)));
typedef __bf16 bf16x8 __attribute__((ext_vector_type(8)));
typedef u32 u32x4 __attribute__((ext_vector_type(4)));

#define NT_ 512
#define LD 264   // 16 rows x 264 u16 (8-el pad)
#define SPIN_GUARD 100000

__device__ __forceinline__ u16 f2bf(float f) {
  unsigned u = __builtin_bit_cast(unsigned, f);
  u += 0x7FFFu + ((u >> 16) & 1u);
  return (u16)(u >> 16);
}
__device__ __forceinline__ float bf2f(u16 h) {
  unsigned u = ((unsigned)h) << 16;
  return __builtin_bit_cast(float, u);
}
__device__ __forceinline__ f32x4 splat4(float b) { f32x4 v = {b, b, b, b}; return v; }
__device__ __forceinline__ bf16x8 asb(uint4 v) { return __builtin_bit_cast(bf16x8, v); }
__device__ __forceinline__ float sigf(float v) { return 1.0f / (1.0f + exp2f(-1.44269504f * v)); }
__device__ __forceinline__ float tanhf_(float v) { float e = exp2f(2.88539008f * v); return 1.0f - 2.0f / (e + 1.0f); }

// raw barrier: LDS-visibility only, NO vmcnt drain (keeps publishes/prefetch
// in flight across the barrier).
__device__ __forceinline__ void barL() {
  asm volatile("s_waitcnt lgkmcnt(0)\n\ts_barrier" ::: "memory");
}

// fire-and-forget coherent 16B publish (write-through to device-coherent point)
__device__ __forceinline__ void pub4(u32* p, u32x4 v) {
  asm volatile("global_store_dwordx4 %0, %1, off sc0 sc1" :: "v"(p), "v"(v) : "memory");
}

// poll 3 partners' tagged 16B words until all 12 tags == tg. The returned
// regs ARE the fresh data (flag merged with payload). vmcnt(0) inside the asm
// also guarantees: by the time we later publish, all our reads of partners'
// previous-step data have completed (overwrite-safety for the parity buffer).
__device__ __forceinline__ void poll3(const u32* a0, const u32* a1, const u32* a2,
                                      u32 tg, u32x4& r0, u32x4& r1, u32x4& r2) {
  int gdn = 0;
  while (true) {
    u32x4 t0, t1, t2;
    asm volatile(
        "global_load_dwordx4 %0, %3, off sc0 sc1\n\t"
        "global_load_dwordx4 %1, %4, off sc0 sc1\n\t"
        "global_load_dwordx4 %2, %5, off sc0 sc1\n\t"
        "s_waitcnt vmcnt(0)"
        : "=&v"(t0), "=&v"(t1), "=&v"(t2)
        : "v"(a0), "v"(a1), "v"(a2)
        : "memory");
    bool ok = (t0[0] >> 16) == tg && (t0[1] >> 16) == tg &&
              (t0[2] >> 16) == tg && (t0[3] >> 16) == tg &&
              (t1[0] >> 16) == tg && (t1[1] >> 16) == tg &&
              (t1[2] >> 16) == tg && (t1[3] >> 16) == tg &&
              (t2[0] >> 16) == tg && (t2[1] >> 16) == tg &&
              (t2[2] >> 16) == tg && (t2[3] >> 16) == tg;
    if (ok || ++gdn >= SPIN_GUARD) { r0 = t0; r1 = t1; r2 = t2; return; }
  }
}

// ---------------- packing (unchanged) ---------------------------------------
__global__ void k_pack_g(const float* __restrict__ src, const float* __restrict__ src2,
                         u16* __restrict__ dst) {
  int e = blockIdx.x * 256 + threadIdx.x;  // 262144
  int j = e & 7, lane = (e >> 3) & 63, g = (e >> 9) & 3, ks = (e >> 11) & 7;
  int w = (e >> 14) & 3, s = (e >> 16) & 3;
  int k = ks * 32 + ((lane >> 4) << 3) + j;
  int col = g * 256 + s * 64 + w * 16 + (lane & 15);
  float v = src[k * 1024 + col];
  if (src2) v += src2[k * 1024 + col];
  dst[e] = f2bf(v);
}
__global__ void k_pack_wip(const float* __restrict__ Wip, u16* __restrict__ dst) {
  int e = blockIdx.x * 256 + threadIdx.x;  // 16384
  int j = e & 7, lane = (e >> 3) & 63, n = (e >> 9) & 3, ks2 = (e >> 11) & 1, w = (e >> 12) & 3;
  int k = ks2 * 32 + ((lane >> 4) << 3) + j;
  int col = w * 64 + n * 16 + (lane & 15);
  dst[e] = f2bf(Wip[k * 256 + col]);
}
__global__ void k_pack_wop(const float* __restrict__ Wop, u16* __restrict__ dst) {
  int e = blockIdx.x * 256 + threadIdx.x;  // 16384
  int j = e & 7, lane = (e >> 3) & 63, ks = (e >> 9) & 7, s = (e >> 12) & 3;
  int k = ks * 32 + ((lane >> 4) << 3) + j;
  int col = s * 16 + (lane & 15);
  dst[e] = f2bf(Wop[k * 64 + col]);
}

__global__ void k_lens(const unsigned char* __restrict__ mask, int* __restrict__ skeys) {
  int b = threadIdx.x;
  bool u8 = (mask[1] | mask[2] | mask[3]) != 0;
  int s = 0;
  if (u8) { const unsigned char* row = mask + b * NT_; for (int t = 0; t < NT_; t++) s += row[t] ? 1 : 0; }
  else { const int* row = (const int*)mask + b * NT_; for (int t = 0; t < NT_; t++) s += row[t] ? 1 : 0; }
  skeys[b] = s * 1024 + b;
}

__global__ void k_sort(int* __restrict__ skeys) {
  __shared__ int sk[512];
  int tid = threadIdx.x;
  sk[tid] = skeys[tid];
  __syncthreads();
  for (int k = 2; k <= 512; k <<= 1)
    for (int j = k >> 1; j > 0; j >>= 1) {
      int ixj = tid ^ j;
      if (ixj > tid) {
        int a = sk[tid], b = sk[ixj];
        bool up = ((tid & k) == 0);
        if ((a > b) == up) { sk[tid] = b; sk[ixj] = a; }
      }
      __syncthreads();
    }
  skeys[tid] = sk[tid];
}

// zero tagged buffer with sc0 sc1 stores (must be visible to sc1 polls; tag 0
// is never polled, so stale tags from a previous launch can't alias).
__global__ void k_zero_hpub(u32* __restrict__ hp) {
  int i = blockIdx.x * 256 + threadIdx.x;  // 65536 x uint4 = 1 MB
  u32x4 z = {0u, 0u, 0u, 0u};
  pub4(hp + (size_t)i * 4, z);
}

// ---------------- persistent recurrent kernel ------------------------------
// grid 128 x 256 thr. block b: tile g=(b&7)+((b>>5)<<3), slice s=(b>>3)&3.
// Exchange buffer per tile: 2 parity x 4 slices x 1024 u32; word
// col_local*16 + row holds (bf16 h | tag<<16). Publisher thread (w,lane):
// cols w*16+n16, rows q*4..q*4+3 -> one aligned dwordx4. Tag sequence:
// encoder h(t) -> tag t (t=1..E); decoder h(d) -> tag E+d (d=1..512).
__global__ __launch_bounds__(256, 1) void k_rec4(
    const float* __restrict__ x,
    const u16* __restrict__ whe_p, const u16* __restrict__ wie_p,
    const u16* __restrict__ wd_p, const u16* __restrict__ wip_p,
    const u16* __restrict__ wop_p,
    const float* __restrict__ bip, const float* __restrict__ be,
    const float* __restrict__ Wlp, const float* __restrict__ blp,
    const float* __restrict__ Wle, const float* __restrict__ ble,
    const float* __restrict__ bd, const float* __restrict__ bop,
    const int* __restrict__ skeys,
    u32* __restrict__ hpub, float* __restrict__ out) {
  __shared__ __align__(16) u16 hx[16 * LD];
  __shared__ __align__(16) u16 xps[16 * LD];
  __shared__ __align__(16) u16 xbuf[16 * 72];
  __shared__ int ob_s[16], len_s[16];
  __shared__ float lat_s[256];

  const int tid = threadIdx.x;
  const int w = tid >> 6, lane = tid & 63, q = lane >> 4, n16 = lane & 15;
  const int b = blockIdx.x;
  const int g = (b & 7) + ((b >> 5) << 3);
  const int s = (b >> 3) & 3;

  if (tid < 16) {
    int v = skeys[g * 16 + tid];
    ob_s[tid] = v & 1023;
    len_s[tid] = v >> 10;
  }
  for (int i = tid; i < 16 * LD; i += 256) hx[i] = 0;
  __syncthreads();
  int maxlen = 0;
#pragma unroll
  for (int i = 0; i < 16; i++) maxlen = len_s[i] > maxlen ? len_s[i] : maxlen;
  int mylen[4];
#pragma unroll
  for (int r = 0; r < 4; r++) mylen[r] = len_s[q * 4 + r];

  // ---- resident weights ----
  const uint4* whe4 = (const uint4*)whe_p;
  const uint4* wie4 = (const uint4*)wie_p;
  const uint4* wip4 = (const uint4*)wip_p;
  uint4 wfh[32], wfx[32], wipf[8];
#pragma unroll
  for (int f = 0; f < 32; f++) wfh[f] = whe4[((s * 4 + w) * 32 + f) * 64 + lane];
#pragma unroll
  for (int f = 0; f < 32; f++) wfx[f] = wie4[((s * 4 + w) * 32 + f) * 64 + lane];
#pragma unroll
  for (int f = 0; f < 8; f++) wipf[f] = wip4[(w * 8 + f) * 64 + lane];

  float be_r[4], bipr[4];
#pragma unroll
  for (int gt = 0; gt < 4; gt++) be_r[gt] = be[gt * 256 + s * 64 + w * 16 + n16];
#pragma unroll
  for (int n = 0; n < 4; n++) bipr[n] = bip[w * 64 + n * 16 + n16];

  float creg[4], hreg[4];
#pragma unroll
  for (int r = 0; r < 4; r++) { creg[r] = 0.f; hreg[r] = 0.f; }

  const char* hxb = (const char*)hx;
  const char* xpsb = (const char*)xps;
  u32* hp32 = hpub + (size_t)g * 8192;  // 2 parity x 4 slices x 1024 u32
  const int p0 = (s == 0) ? 1 : 0;
  const int p1 = (s <= 1) ? 2 : 1;
  const int p2 = (s <= 2) ? 3 : 2;
  const int widx = ((tid >> 2) << 4) + ((tid & 3) << 2);
  const int ccl = tid >> 2, qq = tid & 3;
  const int cc0 = p0 * 64 + ccl, cc1 = p1 * 64 + ccl, cc2 = p2 * 64 + ccl;
  u32* pubp = hp32 + s * 1024 + ((w * 16 + n16) << 4) + (q << 2);
  const int mycol = s * 64 + w * 16 + n16;

#define SCAT3()                                  \
  do {                                           \
    hx[(qq * 4 + 0) * LD + cc0] = (u16)r0[0];    \
    hx[(qq * 4 + 1) * LD + cc0] = (u16)r0[1];    \
    hx[(qq * 4 + 2) * LD + cc0] = (u16)r0[2];    \
    hx[(qq * 4 + 3) * LD + cc0] = (u16)r0[3];    \
    hx[(qq * 4 + 0) * LD + cc1] = (u16)r1[0];    \
    hx[(qq * 4 + 1) * LD + cc1] = (u16)r1[1];    \
    hx[(qq * 4 + 2) * LD + cc1] = (u16)r1[2];    \
    hx[(qq * 4 + 3) * LD + cc1] = (u16)r1[3];    \
    hx[(qq * 4 + 0) * LD + cc2] = (u16)r2[0];    \
    hx[(qq * 4 + 1) * LD + cc2] = (u16)r2[1];    \
    hx[(qq * 4 + 2) * LD + cc2] = (u16)r2[2];    \
    hx[(qq * 4 + 3) * LD + cc2] = (u16)r2[3];    \
  } while (0)

  // x prefetch base: row ob, float4 column xc
  const float4* xr4 = (const float4*)x + (size_t)ob_s[tid >> 4] * 8192 + (tid & 15);
  float4 xv = xr4[0];

  // ================= encoder =================
  for (int t = 0; t < maxlen; t++) {
    {
      u64 pv = (u64)f2bf(xv.x) | ((u64)f2bf(xv.y) << 16) |
               ((u64)f2bf(xv.z) << 32) | ((u64)f2bf(xv.w) << 48);
      *(u64*)&xbuf[(tid >> 4) * 72 + (tid & 15) * 4] = pv;
    }
    int tn = (t + 1 < maxlen) ? t + 1 : t;
    float4 xnx = xr4[(size_t)tn * 16];  // prefetch x(t+1), survives raw barriers
    barL();  // S1: xbuf ready
    // xp = leaky(x_t @ Wip + bip)
    f32x4 xacc[4];
#pragma unroll
    for (int n = 0; n < 4; n++) xacc[n] = splat4(bipr[n]);
#pragma unroll
    for (int ks2 = 0; ks2 < 2; ks2++) {
      bf16x8 a = *(const bf16x8*)((const char*)xbuf + n16 * 144 + ks2 * 64 + q * 16);
#pragma unroll
      for (int n = 0; n < 4; n++)
        xacc[n] = __builtin_amdgcn_mfma_f32_16x16x32_bf16(a, asb(wipf[ks2 * 4 + n]), xacc[n], 0, 0, 0);
    }
#pragma unroll
    for (int n = 0; n < 4; n++)
#pragma unroll
      for (int r = 0; r < 4; r++) {
        float v = xacc[n][r];
        v = v >= 0.f ? v : 0.01f * v;
        xps[(q * 4 + r) * LD + w * 64 + n * 16 + n16] = f2bf(v);
      }
    barL();  // S2: xps ready
    // z1 = be + xp @ Wie (no partner data needed -> overlaps partner latency)
    f32x4 acc[4];
#pragma unroll
    for (int gt = 0; gt < 4; gt++) acc[gt] = splat4(be_r[gt]);
#pragma unroll
    for (int ks = 0; ks < 8; ks++) {
      bf16x8 a = *(const bf16x8*)(xpsb + n16 * (LD * 2) + ks * 64 + q * 16);
#pragma unroll
      for (int gt = 0; gt < 4; gt++)
        acc[gt] = __builtin_amdgcn_mfma_f32_16x16x32_bf16(a, asb(wfx[ks * 4 + gt]), acc[gt], 0, 0, 0);
    }
    // exchange: poll partners' tagged h(t) (data IS the flag)
    if (t > 0) {
      const u32* bp = hp32 + ((t & 1) << 12);
      u32x4 r0, r1, r2;
      poll3(bp + p0 * 1024 + widx, bp + p1 * 1024 + widx, bp + p2 * 1024 + widx,
            (u32)t, r0, r1, r2);
      SCAT3();
    }
    barL();  // S4: hx = h(t) full
    // z2 += h @ Whe
#pragma unroll
    for (int ks = 0; ks < 8; ks++) {
      bf16x8 a = *(const bf16x8*)(hxb + n16 * (LD * 2) + ks * 64 + q * 16);
#pragma unroll
      for (int gt = 0; gt < 4; gt++)
        acc[gt] = __builtin_amdgcn_mfma_f32_16x16x32_bf16(a, asb(wfh[ks * 4 + gt]), acc[gt], 0, 0, 0);
    }
    // gates (i,f,g,o) + masked carry
    u16 hb[4];
#pragma unroll
    for (int r = 0; r < 4; r++) {
      float i_ = sigf(acc[0][r]);
      float f_ = sigf(acc[1][r]);
      float g_ = tanhf_(acc[2][r]);
      float o_ = sigf(acc[3][r]);
      float nc = f_ * creg[r] + i_ * g_;
      float nh = o_ * tanhf_(nc);
      bool upd = t < mylen[r];
      creg[r] = upd ? nc : creg[r];
      hreg[r] = upd ? nh : hreg[r];
      hb[r] = f2bf(hreg[r]);
    }
    // publish h(t+1), fire-and-forget (overwrite-safety: our poll this step
    // proved every partner consumed our h(t-1) -- their tag-t publish values
    // were gated by their step-(t-1) poll's vmcnt(0)).
    {
      u32 tgw = (u32)(t + 1) << 16;
      u32x4 pv = {tgw | hb[0], tgw | hb[1], tgw | hb[2], tgw | hb[3]};
      pub4(pubp + (((t + 1) & 1) << 12), pv);
    }
    barL();  // S5: all hx reads (z2) done
#pragma unroll
    for (int r = 0; r < 4; r++) hx[(q * 4 + r) * LD + mycol] = hb[r];
    xv = xnx;
  }

  // final exchange: full h(maxlen)
  {
    const u32* bp = hp32 + ((maxlen & 1) << 12);
    u32x4 r0, r1, r2;
    poll3(bp + p0 * 1024 + widx, bp + p1 * 1024 + widx, bp + p2 * 1024 + widx,
          (u32)maxlen, r0, r1, r2);
    SCAT3();
  }
  barL();

  // ---- latent (redundant per cluster; slice 0 writes) ----
  {
    int m = tid >> 4, j = tid & 15;
    float acc_ = blp[j];
    for (int k = 0; k < 256; k++) acc_ = fmaf(bf2f(hx[m * LD + k]), Wlp[k * 16 + j], acc_);
    if (s == 0) out[16777216 + ob_s[m] * 16 + j] = acc_;
    lat_s[m * 16 + j] = acc_;
  }
  __syncthreads();
  // ---- ctx = leaky(latent@Wle + ble) -> hx (full) ----
  for (int i = tid; i < 4096; i += 256) {
    int m = i >> 8, c = i & 255;
    float v = ble[c];
#pragma unroll
    for (int k = 0; k < 16; k++) v = fmaf(lat_s[m * 16 + k], Wle[k * 256 + c], v);
    v = v >= 0.f ? v : 0.01f * v;
    hx[m * LD + c] = f2bf(v);
  }
  __syncthreads();
#pragma unroll
  for (int r = 0; r < 4; r++) {
    hreg[r] = bf2f(hx[(q * 4 + r) * LD + mycol]);
    creg[r] = hreg[r];
  }

  // ---- decoder resident weights ----
  const uint4* wd4 = (const uint4*)wd_p;
  const uint4* wop4 = (const uint4*)wop_p;
#pragma unroll
  for (int f = 0; f < 32; f++) wfh[f] = wd4[((s * 4 + w) * 32 + f) * 64 + lane];
#pragma unroll
  for (int f = 0; f < 8; f++) wfx[f] = wop4[(s * 8 + f) * 64 + lane];
  float bd_r[4];
#pragma unroll
  for (int gt = 0; gt < 4; gt++) bd_r[gt] = bd[gt * 256 + s * 64 + w * 16 + n16];
  float bop_r = bop[s * 16 + n16];
  int orow[4];
#pragma unroll
  for (int r = 0; r < 4; r++) orow[r] = ob_s[q * 4 + r] << 15;
  const int E = maxlen;

  // ================= decoder =================
  // No enc->dec handshake needed: tag monotonicity makes buffer reuse safe
  // (our d=1 poll of tag E+1 proves partners consumed tag E before we write
  // tag E+2 over it).
  for (int d = 0; d < NT_; d++) {
    if (d > 0) {
      const u32* bp = hp32 + (((E + d) & 1) << 12);
      u32x4 r0, r1, r2;
      poll3(bp + p0 * 1024 + widx, bp + p1 * 1024 + widx, bp + p2 * 1024 + widx,
            (u32)(E + d), r0, r1, r2);
      SCAT3();
    }
    barL();  // A: hx = h(d) full
    // pred_{d-1} = h_d @ Wop cols s*16.. (all waves compute, w0 writes)
    f32x4 pacc = splat4(0.f);
#pragma unroll
    for (int ks = 0; ks < 8; ks++) {
      bf16x8 a = *(const bf16x8*)(hxb + n16 * (LD * 2) + ks * 64 + q * 16);
      pacc = __builtin_amdgcn_mfma_f32_16x16x32_bf16(a, asb(wfx[ks]), pacc, 0, 0, 0);
    }
    if (w == 0 && d > 0) {
#pragma unroll
      for (int r = 0; r < 4; r++)
        out[orow[r] + ((d - 1) << 6) + (s << 4) + n16] = pacc[r] + bop_r;
    }
    // z = h_d @ Wd_s + bd_s
    f32x4 acc[4];
#pragma unroll
    for (int gt = 0; gt < 4; gt++) acc[gt] = splat4(bd_r[gt]);
#pragma unroll
    for (int ks = 0; ks < 8; ks++) {
      bf16x8 a = *(const bf16x8*)(hxb + n16 * (LD * 2) + ks * 64 + q * 16);
#pragma unroll
      for (int gt = 0; gt < 4; gt++)
        acc[gt] = __builtin_amdgcn_mfma_f32_16x16x32_bf16(a, asb(wfh[ks * 4 + gt]), acc[gt], 0, 0, 0);
    }
    u16 hb[4];
#pragma unroll
    for (int r = 0; r < 4; r++) {
      float i_ = sigf(acc[0][r]);
      float f_ = sigf(acc[1][r]);
      float g_ = tanhf_(acc[2][r]);
      float o_ = sigf(acc[3][r]);
      float nc = f_ * creg[r] + i_ * g_;
      creg[r] = nc;
      hreg[r] = o_ * tanhf_(nc);
      hb[r] = f2bf(hreg[r]);
    }
    {
      u32 tgw = (u32)(E + d + 1) << 16;
      u32x4 pv = {tgw | hb[0], tgw | hb[1], tgw | hb[2], tgw | hb[3]};
      pub4(pubp + (((E + d + 1) & 1) << 12), pv);
    }
    barL();  // B: hx reads done
#pragma unroll
    for (int r = 0; r < 4; r++) hx[(q * 4 + r) * LD + mycol] = hb[r];
  }
  // final: h(512) -> recon[:,511]
  {
    const u32* bp = hp32 + (((E + NT_) & 1) << 12);
    u32x4 r0, r1, r2;
    poll3(bp + p0 * 1024 + widx, bp + p1 * 1024 + widx, bp + p2 * 1024 + widx,
          (u32)(E + NT_), r0, r1, r2);
    SCAT3();
  }
  barL();
  if (w == 0) {
    f32x4 pacc = splat4(0.f);
#pragma unroll
    for (int ks = 0; ks < 8; ks++) {
      bf16x8 a = *(const bf16x8*)(hxb + n16 * (LD * 2) + ks * 64 + q * 16);
      pacc = __builtin_amdgcn_mfma_f32_16x16x32_bf16(a, asb(wfx[ks]), pacc, 0, 0, 0);
    }
#pragma unroll
    for (int r = 0; r < 4; r++)
      out[orow[r] + (511 << 6) + (s << 4) + n16] = pacc[r] + bop_r;
  }
#undef SCAT3
}

// ---------------- host ------------------------------------------------------
// layout (bytes): WHE 0 | WIE 524288 | WD 1048576 | WIP 1572864 | WOP 1605632 |
// HPUB 1638400..2686976 (32 tiles x 32 KB tagged u32) | SKEYS
#define OFF_WHE 0ull
#define OFF_WIE 524288ull
#define OFF_WD 1048576ull
#define OFF_WIP 1572864ull
#define OFF_WOP 1605632ull
#define OFF_HPUB 1638400ull
#define OFF_SKEYS 2686976ull
#define MIN_WS 2689024ull

extern "C" void kernel_launch(void* const* d_in, const int* in_sizes, int n_in,
                              void* d_out, int out_size, void* d_ws, size_t ws_size,
                              hipStream_t stream) {
  const float* x = (const float*)d_in[0];
  const unsigned char* mask = (const unsigned char*)d_in[1];
  const float* Wip = (const float*)d_in[2];
  const float* bip = (const float*)d_in[3];
  const float* Wie = (const float*)d_in[4];
  const float* Whe = (const float*)d_in[5];
  const float* be = (const float*)d_in[6];
  const float* Wlp = (const float*)d_in[7];
  const float* blp = (const float*)d_in[8];
  const float* Wle = (const float*)d_in[9];
  const float* ble = (const float*)d_in[10];
  const float* Wid = (const float*)d_in[11];
  const float* Whd = (const float*)d_in[12];
  const float* bd = (const float*)d_in[13];
  const float* Wop = (const float*)d_in[14];
  const float* bop = (const float*)d_in[15];
  float* out = (float*)d_out;
  char* ws = (char*)d_ws;

  if (ws_size < MIN_WS) return;

  u16* whe_p = (u16*)(ws + OFF_WHE);
  u16* wie_p = (u16*)(ws + OFF_WIE);
  u16* wd_p = (u16*)(ws + OFF_WD);
  u16* wip_p = (u16*)(ws + OFF_WIP);
  u16* wop_p = (u16*)(ws + OFF_WOP);
  u32* hpub = (u32*)(ws + OFF_HPUB);
  int* skeys = (int*)(ws + OFF_SKEYS);

  k_pack_g<<<1024, 256, 0, stream>>>(Whe, nullptr, whe_p);
  k_pack_g<<<1024, 256, 0, stream>>>(Wie, nullptr, wie_p);
  k_pack_g<<<1024, 256, 0, stream>>>(Wid, Whd, wd_p);
  k_pack_wip<<<64, 256, 0, stream>>>(Wip, wip_p);
  k_pack_wop<<<64, 256, 0, stream>>>(Wop, wop_p);
  k_lens<<<1, 512, 0, stream>>>(mask, skeys);
  k_sort<<<1, 512, 0, stream>>>(skeys);
  k_zero_hpub<<<256, 256, 0, stream>>>(hpub);

  k_rec4<<<128, 256, 0, stream>>>(x, whe_p, wie_p, wd_p, wip_p, wop_p,
                                  bip, be, Wlp, blp, Wle, ble, bd, bop,
                                  skeys, hpub, out);
}